// Round 1
// baseline (150.822 us; speedup 1.0000x reference)
//
#include <hip/hip_runtime.h>
#include <math.h>

// WindingEmbedding: rows = 32768 (B=8, S=4096), D=1024, W=8 windings, F=16 feats.
// out[row][d] = ((emb - mu) * rsqrt(var+eps)) * gamma + beta
// emb[row][d] = sum_f feats[row][f] * pw[d][f] + pb[d]
// Analytic stats: mu = f.meanW + mean_b ; E[emb^2] = f'Mf + 2 f.c + mean_b2
//
// ws layout (floats):
//   [0..255]   M[j][i]   = (1/D) sum_d pw[d][j] pw[d][i]
//   [256..271] meanW[f]  = (1/D) sum_d pw[d][f]
//   [272..287] c[f]      = (1/D) sum_d pw[d][f] pb[d]
//   [288] mean_b, [289] mean_b2

__global__ __launch_bounds__(256) void wind_stats(const float* __restrict__ pw,
                                                  const float* __restrict__ pb,
                                                  float* __restrict__ ws) {
  const int t = threadIdx.x;
  const int f = t >> 4, g = t & 15;
  float m0 = 0.f, m1 = 0.f, m2 = 0.f, m3 = 0.f;
  float mw = 0.f, cc = 0.f, b1 = 0.f, b2 = 0.f;
  for (int d = 0; d < 1024; d += 4) {
    const float wf0 = pw[(d + 0) * 16 + f], wg0 = pw[(d + 0) * 16 + g];
    const float wf1 = pw[(d + 1) * 16 + f], wg1 = pw[(d + 1) * 16 + g];
    const float wf2 = pw[(d + 2) * 16 + f], wg2 = pw[(d + 2) * 16 + g];
    const float wf3 = pw[(d + 3) * 16 + f], wg3 = pw[(d + 3) * 16 + g];
    m0 = fmaf(wf0, wg0, m0);
    m1 = fmaf(wf1, wg1, m1);
    m2 = fmaf(wf2, wg2, m2);
    m3 = fmaf(wf3, wg3, m3);
    if (g == 0) {
      const float bb0 = pb[d + 0], bb1 = pb[d + 1];
      const float bb2 = pb[d + 2], bb3 = pb[d + 3];
      mw += (wf0 + wf1) + (wf2 + wf3);
      cc = fmaf(wf0, bb0, fmaf(wf1, bb1, fmaf(wf2, bb2, fmaf(wf3, bb3, cc))));
      if (f == 0) {
        b1 += (bb0 + bb1) + (bb2 + bb3);
        b2 = fmaf(bb0, bb0, fmaf(bb1, bb1, fmaf(bb2, bb2, fmaf(bb3, bb3, b2))));
      }
    }
  }
  const float inv = 1.0f / 1024.0f;
  ws[t] = ((m0 + m1) + (m2 + m3)) * inv;
  if (g == 0) {
    ws[256 + f] = mw * inv;
    ws[272 + f] = cc * inv;
    if (f == 0) {
      ws[288] = b1 * inv;
      ws[289] = b2 * inv;
    }
  }
}

#define TWO_PI 6.28318530717958647692f

__global__ __launch_bounds__(256) void wind_main(const int* __restrict__ x,
                                                 const float* __restrict__ winds,
                                                 const float* __restrict__ pw,
                                                 const float* __restrict__ pb,
                                                 const float* __restrict__ gamma,
                                                 const float* __restrict__ beta,
                                                 const float* __restrict__ ws,
                                                 float* __restrict__ out) {
  __shared__ float lds[16][20];  // 16 rows x (16 feats + mu + rsig), padded
  const int tid = threadIdx.x;
  const int base = blockIdx.x * 16;
  const int d0 = tid << 2;  // this thread's 4 output dims

  // Register-cache projection rows for dims d0..d0+3 (64 floats), plus bias/affine.
  float4 wreg[4][4];
#pragma unroll
  for (int r = 0; r < 4; ++r) {
#pragma unroll
    for (int c = 0; c < 4; ++c) {
      wreg[r][c] = reinterpret_cast<const float4*>(pw)[(d0 + r) * 4 + c];
    }
  }
  const float4 pbv = reinterpret_cast<const float4*>(pb)[tid];
  const float4 gv = reinterpret_cast<const float4*>(gamma)[tid];
  const float4 bv = reinterpret_cast<const float4*>(beta)[tid];

  // ---------------- Phase A: per-row stats (16 lanes per row) ----------------
  const int rl = tid >> 4;  // local row 0..15
  const int j = tid & 15;   // feature index this lane owns
  const int row = base + rl;
  const float tf = (float)x[row] * (1.0f / 50257.0f);

  float feats[16];
#pragma unroll
  for (int w = 0; w < 8; ++w) {
    float s, c;
    sincosf(TWO_PI * tf * winds[w], &s, &c);
    feats[2 * w] = c;
    feats[2 * w + 1] = s;
  }
  // feats[j] without runtime register indexing (rule #20): recompute one sincos.
  float sj, cj;
  sincosf(TWO_PI * tf * winds[j >> 1], &sj, &cj);
  const float fj = (j & 1) ? sj : cj;

  float dotm = 0.f;
#pragma unroll
  for (int i = 0; i < 16; ++i) dotm = fmaf(ws[j * 16 + i], feats[i], dotm);

  float pE = fj * fmaf(2.0f, ws[272 + j], dotm);  // f_j*(Mf)_j + 2 f_j c_j
  float pM = fj * ws[256 + j];
#pragma unroll
  for (int off = 1; off < 16; off <<= 1) {
    pE += __shfl_xor(pE, off);
    pM += __shfl_xor(pM, off);
  }
  const float mu = pM + ws[288];
  const float var = (pE + ws[289]) - mu * mu;
  const float rs = rsqrtf(var + 1e-5f);

  lds[rl][j] = fj;
  if (j == 0) lds[rl][16] = mu;
  if (j == 1) lds[rl][17] = rs;
  __syncthreads();

  // ---------------- Phase B: coalesced output, 4 dims/thread ----------------
  float* o = out + (size_t)base * 1024 + d0;
#pragma unroll 4
  for (int r = 0; r < 16; ++r) {
    const float4 F0 = *reinterpret_cast<const float4*>(&lds[r][0]);
    const float4 F1 = *reinterpret_cast<const float4*>(&lds[r][4]);
    const float4 F2 = *reinterpret_cast<const float4*>(&lds[r][8]);
    const float4 F3 = *reinterpret_cast<const float4*>(&lds[r][12]);
    const float mu_r = lds[r][16];
    const float rs_r = lds[r][17];

    float e[4];
#pragma unroll
    for (int k = 0; k < 4; ++k) {
      float a = (k == 0) ? pbv.x : (k == 1) ? pbv.y : (k == 2) ? pbv.z : pbv.w;
      a = fmaf(wreg[k][0].x, F0.x, a);
      a = fmaf(wreg[k][0].y, F0.y, a);
      a = fmaf(wreg[k][0].z, F0.z, a);
      a = fmaf(wreg[k][0].w, F0.w, a);
      a = fmaf(wreg[k][1].x, F1.x, a);
      a = fmaf(wreg[k][1].y, F1.y, a);
      a = fmaf(wreg[k][1].z, F1.z, a);
      a = fmaf(wreg[k][1].w, F1.w, a);
      a = fmaf(wreg[k][2].x, F2.x, a);
      a = fmaf(wreg[k][2].y, F2.y, a);
      a = fmaf(wreg[k][2].z, F2.z, a);
      a = fmaf(wreg[k][2].w, F2.w, a);
      a = fmaf(wreg[k][3].x, F3.x, a);
      a = fmaf(wreg[k][3].y, F3.y, a);
      a = fmaf(wreg[k][3].z, F3.z, a);
      a = fmaf(wreg[k][3].w, F3.w, a);
      e[k] = a;
    }
    const float s0 = gv.x * rs_r, s1 = gv.y * rs_r, s2 = gv.z * rs_r, s3 = gv.w * rs_r;
    float4 res;
    res.x = fmaf(e[0], s0, fmaf(-mu_r, s0, bv.x));
    res.y = fmaf(e[1], s1, fmaf(-mu_r, s1, bv.y));
    res.z = fmaf(e[2], s2, fmaf(-mu_r, s2, bv.z));
    res.w = fmaf(e[3], s3, fmaf(-mu_r, s3, bv.w));
    *reinterpret_cast<float4*>(o + (size_t)r * 1024) = res;
  }
}

extern "C" void kernel_launch(void* const* d_in, const int* in_sizes, int n_in,
                              void* d_out, int out_size, void* d_ws, size_t ws_size,
                              hipStream_t stream) {
  const int* x = (const int*)d_in[0];
  const float* winds = (const float*)d_in[1];
  const float* pw = (const float*)d_in[2];
  const float* pb = (const float*)d_in[3];
  const float* gamma = (const float*)d_in[4];
  const float* beta = (const float*)d_in[5];
  float* out = (float*)d_out;
  float* ws = (float*)d_ws;

  const int rows = in_sizes[0];  // 32768
  wind_stats<<<1, 256, 0, stream>>>(pw, pb, ws);
  wind_main<<<rows / 16, 256, 0, stream>>>(x, winds, pw, pb, gamma, beta, ws, out);
}

// Round 2
// 78.865 us; speedup vs baseline: 1.9124x; 1.9124x over previous
//
#include <hip/hip_runtime.h>
#include <math.h>

// WindingEmbedding: rows = 32768 (B=8, S=4096), D=1024, W=8 windings, F=16 feats.
// out[row][d] = ((emb - mu) * rsqrt(var+eps)) * gamma + beta
// emb[row][d] = sum_f feats[row][f] * pw[d][f] + pb[d]
// Analytic stats: mu = f.meanW + mean_b ; E[emb^2] = f'Mf + 2 f.c + mean_b2
//
// ws layout (floats):
//   partials: ws[b*320 + e], b in [0,64), e in [0,290)
//   finals at ws+20480:
//     [0..255]   M[j][i]   = (1/D) sum_d pw[d][j] pw[d][i]
//     [256..271] meanW[f]  = (1/D) sum_d pw[d][f]
//     [272..287] c[f]      = (1/D) sum_d pw[d][f] pb[d]
//     [288] mean_b, [289] mean_b2

#define PSTRIDE 320
#define FINAL_OFF 20480

__global__ __launch_bounds__(256) void stats_partial(const float* __restrict__ pw,
                                                     const float* __restrict__ pb,
                                                     float* __restrict__ ws) {
  const int t = threadIdx.x;
  const int b = blockIdx.x;         // covers d in [b*16, b*16+16)
  const int f = t >> 4, g = t & 15;
  const int d0 = b * 16;

  float m = 0.f, mw = 0.f, cc = 0.f, b1 = 0.f, b2 = 0.f;
#pragma unroll
  for (int k = 0; k < 16; ++k) {
    const int d = d0 + k;
    const float wf = pw[d * 16 + f];
    const float wg = pw[d * 16 + g];
    m = fmaf(wf, wg, m);
    if (g == 0) {
      const float bb = pb[d];
      mw += wf;
      cc = fmaf(wf, bb, cc);
      if (f == 0) {
        b1 += bb;
        b2 = fmaf(bb, bb, b2);
      }
    }
  }
  const float inv = 1.0f / 1024.0f;
  float* p = ws + b * PSTRIDE;
  p[t] = m * inv;
  if (g == 0) {
    p[256 + f] = mw * inv;
    p[272 + f] = cc * inv;
    if (f == 0) {
      p[288] = b1 * inv;
      p[289] = b2 * inv;
    }
  }
}

__global__ __launch_bounds__(320) void stats_reduce(float* __restrict__ ws) {
  const int t = threadIdx.x;  // 0..319 (only 0..289 meaningful)
  float s = 0.f;
#pragma unroll
  for (int b = 0; b < 64; ++b) s += ws[b * PSTRIDE + t];
  ws[FINAL_OFF + t] = s;
}

#define TWO_PI 6.28318530717958647692f

__global__ __launch_bounds__(256) void wind_main(const int* __restrict__ x,
                                                 const float* __restrict__ winds,
                                                 const float* __restrict__ pw,
                                                 const float* __restrict__ pb,
                                                 const float* __restrict__ gamma,
                                                 const float* __restrict__ beta,
                                                 const float* __restrict__ ws,
                                                 float* __restrict__ out) {
  __shared__ float lds[16][20];  // 16 rows x (16 feats + mu + rsig), padded
  const int tid = threadIdx.x;
  const int base = blockIdx.x * 16;
  const int d0 = tid << 2;  // this thread's 4 output dims

  // Register-cache projection rows for dims d0..d0+3 (64 floats), plus bias/affine.
  float4 wreg[4][4];
#pragma unroll
  for (int r = 0; r < 4; ++r) {
#pragma unroll
    for (int c = 0; c < 4; ++c) {
      wreg[r][c] = reinterpret_cast<const float4*>(pw)[(d0 + r) * 4 + c];
    }
  }
  const float4 pbv = reinterpret_cast<const float4*>(pb)[tid];
  const float4 gv = reinterpret_cast<const float4*>(gamma)[tid];
  const float4 bv = reinterpret_cast<const float4*>(beta)[tid];

  // ---------------- Phase A: per-row stats (16 lanes per row) ----------------
  const int rl = tid >> 4;  // local row 0..15
  const int j = tid & 15;   // feature index this lane owns
  const int row = base + rl;
  const float tf = (float)x[row] * (1.0f / 50257.0f);

  float feats[16];
#pragma unroll
  for (int w = 0; w < 8; ++w) {
    float s, c;
    sincosf(TWO_PI * tf * winds[w], &s, &c);
    feats[2 * w] = c;
    feats[2 * w + 1] = s;
  }
  // feats[j] without runtime register indexing (rule #20): recompute one sincos.
  float sj, cj;
  sincosf(TWO_PI * tf * winds[j >> 1], &sj, &cj);
  const float fj = (j & 1) ? sj : cj;

  float dotm = 0.f;
#pragma unroll
  for (int i = 0; i < 16; ++i) dotm = fmaf(ws[j * 16 + i], feats[i], dotm);

  float pE = fj * fmaf(2.0f, ws[272 + j], dotm);  // f_j*(Mf)_j + 2 f_j c_j
  float pM = fj * ws[256 + j];
#pragma unroll
  for (int off = 1; off < 16; off <<= 1) {
    pE += __shfl_xor(pE, off);
    pM += __shfl_xor(pM, off);
  }
  const float mu = pM + ws[288];
  const float var = (pE + ws[289]) - mu * mu;
  const float rs = rsqrtf(var + 1e-5f);

  lds[rl][j] = fj;
  if (j == 0) lds[rl][16] = mu;
  if (j == 1) lds[rl][17] = rs;
  __syncthreads();

  // ---------------- Phase B: coalesced output, 4 dims/thread ----------------
  float* o = out + (size_t)base * 1024 + d0;
#pragma unroll 4
  for (int r = 0; r < 16; ++r) {
    const float4 F0 = *reinterpret_cast<const float4*>(&lds[r][0]);
    const float4 F1 = *reinterpret_cast<const float4*>(&lds[r][4]);
    const float4 F2 = *reinterpret_cast<const float4*>(&lds[r][8]);
    const float4 F3 = *reinterpret_cast<const float4*>(&lds[r][12]);
    const float mu_r = lds[r][16];
    const float rs_r = lds[r][17];

    float e[4];
#pragma unroll
    for (int k = 0; k < 4; ++k) {
      float a = (k == 0) ? pbv.x : (k == 1) ? pbv.y : (k == 2) ? pbv.z : pbv.w;
      a = fmaf(wreg[k][0].x, F0.x, a);
      a = fmaf(wreg[k][0].y, F0.y, a);
      a = fmaf(wreg[k][0].z, F0.z, a);
      a = fmaf(wreg[k][0].w, F0.w, a);
      a = fmaf(wreg[k][1].x, F1.x, a);
      a = fmaf(wreg[k][1].y, F1.y, a);
      a = fmaf(wreg[k][1].z, F1.z, a);
      a = fmaf(wreg[k][1].w, F1.w, a);
      a = fmaf(wreg[k][2].x, F2.x, a);
      a = fmaf(wreg[k][2].y, F2.y, a);
      a = fmaf(wreg[k][2].z, F2.z, a);
      a = fmaf(wreg[k][2].w, F2.w, a);
      a = fmaf(wreg[k][3].x, F3.x, a);
      a = fmaf(wreg[k][3].y, F3.y, a);
      a = fmaf(wreg[k][3].z, F3.z, a);
      a = fmaf(wreg[k][3].w, F3.w, a);
      e[k] = a;
    }
    const float s0 = gv.x * rs_r, s1 = gv.y * rs_r, s2 = gv.z * rs_r, s3 = gv.w * rs_r;
    float4 res;
    res.x = fmaf(e[0], s0, fmaf(-mu_r, s0, bv.x));
    res.y = fmaf(e[1], s1, fmaf(-mu_r, s1, bv.y));
    res.z = fmaf(e[2], s2, fmaf(-mu_r, s2, bv.z));
    res.w = fmaf(e[3], s3, fmaf(-mu_r, s3, bv.w));
    *reinterpret_cast<float4*>(o + (size_t)r * 1024) = res;
  }
}

extern "C" void kernel_launch(void* const* d_in, const int* in_sizes, int n_in,
                              void* d_out, int out_size, void* d_ws, size_t ws_size,
                              hipStream_t stream) {
  const int* x = (const int*)d_in[0];
  const float* winds = (const float*)d_in[1];
  const float* pw = (const float*)d_in[2];
  const float* pb = (const float*)d_in[3];
  const float* gamma = (const float*)d_in[4];
  const float* beta = (const float*)d_in[5];
  float* out = (float*)d_out;
  float* ws = (float*)d_ws;

  const int rows = in_sizes[0];  // 32768
  stats_partial<<<64, 256, 0, stream>>>(pw, pb, ws);
  stats_reduce<<<1, 320, 0, stream>>>(ws);
  wind_main<<<rows / 16, 256, 0, stream>>>(x, winds, pw, pb, gamma, beta,
                                           ws + FINAL_OFF, out);
}

// Round 3
// 45.782 us; speedup vs baseline: 3.2944x; 1.7226x over previous
//
#include <hip/hip_runtime.h>
#include <math.h>

// WindingEmbedding, fully fused single kernel.
// rows = 32768 (B=8, S=4096), D=1024, W=8 windings, F=16 feats.
// out[row][d] = ((emb - mu) * rsqrt(var+eps)) * gamma + beta
// emb[row][d] = sum_f feats[row][f] * pw[d][f] + pb[d]
//
// Block = 256 threads, 16 rows/block. Thread t owns output dims 4t..4t+3
// (64 pw floats register-cached, reused across all 16 rows). Rows processed
// in two halves of 8 to keep emb-in-register pressure at 32 VGPRs.
// Row stats via direct reduction: per-thread (sum, sumsq) partials ->
// 6-step __shfl_xor wave reduce -> 4-wave LDS combine. No stats pre-kernels.

#define TWO_PI 6.28318530717958647692f
#define INV_VOCAB (1.0f / 50257.0f)
#define INV_D (1.0f / 1024.0f)

__global__ __launch_bounds__(256) void wind_fused(const int* __restrict__ x,
                                                  const float* __restrict__ winds,
                                                  const float* __restrict__ pw,
                                                  const float* __restrict__ pb,
                                                  const float* __restrict__ gamma,
                                                  const float* __restrict__ beta,
                                                  float* __restrict__ out) {
  __shared__ __align__(16) float feat[16][20];  // 16 rows x 16 feats (pad 20: 80B row, 16B-aligned)
  __shared__ float red[2][4][8][2];             // [half][wave][row][sum|sumsq]

  const int tid = threadIdx.x;
  const int wave = tid >> 6;
  const int lane = tid & 63;
  const int base = blockIdx.x * 16;
  const int d0 = tid << 2;  // this thread's 4 output dims

  // Register-cache projection rows for dims d0..d0+3 (64 floats) + bias/affine.
  float4 wreg[4][4];
#pragma unroll
  for (int r = 0; r < 4; ++r)
#pragma unroll
    for (int c = 0; c < 4; ++c)
      wreg[r][c] = reinterpret_cast<const float4*>(pw)[(d0 + r) * 4 + c];
  const float4 pbv = reinterpret_cast<const float4*>(pb)[tid];
  const float4 gv = reinterpret_cast<const float4*>(gamma)[tid];
  const float4 bv = reinterpret_cast<const float4*>(beta)[tid];

  // ---- Phase A: one sincos per thread stages the 16x16 feature tile ----
  {
    const int rl = tid >> 4;  // row 0..15
    const int j = tid & 15;   // feature index
    const float tf = (float)x[base + rl] * INV_VOCAB;
    float s, c;
    sincosf(TWO_PI * tf * winds[j >> 1], &s, &c);
    feat[rl][j] = (j & 1) ? s : c;  // interleaved [cos0,sin0,cos1,sin1,...]
  }
  __syncthreads();

  // ---- Two halves of 8 rows each ----
#pragma unroll
  for (int h = 0; h < 2; ++h) {
    float er[8][4];
    float sr[8], qr[8];

#pragma unroll
    for (int r = 0; r < 8; ++r) {
      const int rr = h * 8 + r;
      const float4 F0 = *reinterpret_cast<const float4*>(&feat[rr][0]);
      const float4 F1 = *reinterpret_cast<const float4*>(&feat[rr][4]);
      const float4 F2 = *reinterpret_cast<const float4*>(&feat[rr][8]);
      const float4 F3 = *reinterpret_cast<const float4*>(&feat[rr][12]);
#pragma unroll
      for (int k = 0; k < 4; ++k) {
        float a = (k == 0) ? pbv.x : (k == 1) ? pbv.y : (k == 2) ? pbv.z : pbv.w;
        a = fmaf(wreg[k][0].x, F0.x, a);
        a = fmaf(wreg[k][0].y, F0.y, a);
        a = fmaf(wreg[k][0].z, F0.z, a);
        a = fmaf(wreg[k][0].w, F0.w, a);
        a = fmaf(wreg[k][1].x, F1.x, a);
        a = fmaf(wreg[k][1].y, F1.y, a);
        a = fmaf(wreg[k][1].z, F1.z, a);
        a = fmaf(wreg[k][1].w, F1.w, a);
        a = fmaf(wreg[k][2].x, F2.x, a);
        a = fmaf(wreg[k][2].y, F2.y, a);
        a = fmaf(wreg[k][2].z, F2.z, a);
        a = fmaf(wreg[k][2].w, F2.w, a);
        a = fmaf(wreg[k][3].x, F3.x, a);
        a = fmaf(wreg[k][3].y, F3.y, a);
        a = fmaf(wreg[k][3].z, F3.z, a);
        a = fmaf(wreg[k][3].w, F3.w, a);
        er[r][k] = a;
      }
      sr[r] = (er[r][0] + er[r][1]) + (er[r][2] + er[r][3]);
      float q = er[r][0] * er[r][0];
      q = fmaf(er[r][1], er[r][1], q);
      q = fmaf(er[r][2], er[r][2], q);
      q = fmaf(er[r][3], er[r][3], q);
      qr[r] = q;
    }

    // Wave-level butterfly reduce (64 lanes)
#pragma unroll
    for (int r = 0; r < 8; ++r) {
#pragma unroll
      for (int off = 1; off < 64; off <<= 1) {
        sr[r] += __shfl_xor(sr[r], off);
        qr[r] += __shfl_xor(qr[r], off);
      }
    }
    if (lane == 0) {
#pragma unroll
      for (int r = 0; r < 8; ++r) {
        red[h][wave][r][0] = sr[r];
        red[h][wave][r][1] = qr[r];
      }
    }
    __syncthreads();

    // Finalize + coalesced store (every thread redundantly combines 4 waves)
    float* o = out + (size_t)(base + h * 8) * 1024 + d0;
#pragma unroll
    for (int r = 0; r < 8; ++r) {
      const float s = (red[h][0][r][0] + red[h][1][r][0]) +
                      (red[h][2][r][0] + red[h][3][r][0]);
      const float q = (red[h][0][r][1] + red[h][1][r][1]) +
                      (red[h][2][r][1] + red[h][3][r][1]);
      const float mu = s * INV_D;
      const float var = fmaf(q, INV_D, -mu * mu);
      const float rs = rsqrtf(var + 1e-5f);
      const float s0 = gv.x * rs, s1 = gv.y * rs, s2 = gv.z * rs, s3 = gv.w * rs;
      float4 res;
      res.x = fmaf(er[r][0], s0, fmaf(-mu, s0, bv.x));
      res.y = fmaf(er[r][1], s1, fmaf(-mu, s1, bv.y));
      res.z = fmaf(er[r][2], s2, fmaf(-mu, s2, bv.z));
      res.w = fmaf(er[r][3], s3, fmaf(-mu, s3, bv.w));
      *reinterpret_cast<float4*>(o + (size_t)r * 1024) = res;
    }
  }
}

extern "C" void kernel_launch(void* const* d_in, const int* in_sizes, int n_in,
                              void* d_out, int out_size, void* d_ws, size_t ws_size,
                              hipStream_t stream) {
  const int* x = (const int*)d_in[0];
  const float* winds = (const float*)d_in[1];
  const float* pw = (const float*)d_in[2];
  const float* pb = (const float*)d_in[3];
  const float* gamma = (const float*)d_in[4];
  const float* beta = (const float*)d_in[5];
  float* out = (float*)d_out;

  const int rows = in_sizes[0];  // 32768
  wind_fused<<<rows / 16, 256, 0, stream>>>(x, winds, pw, pb, gamma, beta, out);
}